// Round 1
// baseline (2268.640 us; speedup 1.0000x reference)
//
#include <hip/hip_runtime.h>

// HarmonicRNN: enc GRU (T=32, in=16000, H=512) -> dec GRU (510 steps, in=6) + linear(6).
// k0: zero control/out, seed gi with enc_b_ih.
// k1: gi[t][row] = enc_w_ih @ x_t (+bias), K-split GEMM with atomicAdd.
// k2: persistent 16-WG cooperative kernel; weights in VGPRs (8x16 fp32/thread);
//     per-step: agent-load h -> reg FMA -> shfl butterfly -> gates -> agent-store h slice
//     -> grid barrier (agent-scope monotonic counter).

#define HID 512
#define G3  1536
#define NWG 16
#define TPB 384   // 12 rgroups x 32 cgroups
#define JPW 32    // h indices per WG
#define RPW 96    // rows per WG (3 gates x 32)

#define WS_CNT  0
#define WS_HEX  64     // h_exch[2][512]
#define WS_PMSG 1088   // pmsg[2][16][8]
#define WS_GI   4096   // gi_enc[32][1536]

__device__ __forceinline__ float sigmf(float x) { return 1.0f / (1.0f + expf(-x)); }

__device__ __forceinline__ void st_agent(float* p, float v) {
  __hip_atomic_store((unsigned int*)p, __float_as_uint(v), __ATOMIC_RELAXED, __HIP_MEMORY_SCOPE_AGENT);
}
__device__ __forceinline__ float ld_agent(const float* p) {
  unsigned int u = __hip_atomic_load((const unsigned int*)p, __ATOMIC_RELAXED, __HIP_MEMORY_SCOPE_AGENT);
  return __uint_as_float(u);
}
__device__ __forceinline__ void ld_agent2(const float* p, float& a, float& b) {
  unsigned long long u = __hip_atomic_load((const unsigned long long*)p, __ATOMIC_RELAXED, __HIP_MEMORY_SCOPE_AGENT);
  a = __uint_as_float((unsigned int)u);
  b = __uint_as_float((unsigned int)(u >> 32));
}

__global__ __launch_bounds__(256) void k0_init(float* __restrict__ ws, float* __restrict__ out,
                                               const float* __restrict__ enc_b_ih) {
  int i = blockIdx.x * 256 + threadIdx.x;
  int n = gridDim.x * 256;
  for (int j = i; j < 4096; j += n) ws[j] = 0.0f;
  for (int j = i; j < 32 * G3; j += n) ws[WS_GI + j] = enc_b_ih[j % G3];
  for (int j = i; j < 3073; j += n) out[j] = 0.0f;
}

#define KB 160
__global__ __launch_bounds__(256) void k1_gemm(const float* __restrict__ x,
                                               const float* __restrict__ wih,
                                               float* __restrict__ ws) {
  __shared__ float lw[64][KB + 4];
  __shared__ float lx[32][KB + 4];
  const int m0  = blockIdx.x * 64;     // 24 row blocks
  const int k00 = blockIdx.y * 1600;   // 10 K splits
  const int t   = threadIdx.x;
  const int rg  = t >> 4;              // 16 row groups of 4
  const int tg  = t & 15;              // 16 t groups of 2
  float acc[4][2] = {{0.f,0.f},{0.f,0.f},{0.f,0.f},{0.f,0.f}};
  for (int c = 0; c < 10; ++c) {
    const int kc = k00 + c * KB;
    __syncthreads();
    #pragma unroll
    for (int j = 0; j < 10; ++j) {
      int idx = t + j * 256;           // 64*40 float4
      int r = idx / 40, c4 = idx % 40;
      float4 v = *reinterpret_cast<const float4*>(wih + (long)(m0 + r) * 16000 + kc + c4 * 4);
      *reinterpret_cast<float4*>(&lw[r][c4 * 4]) = v;
    }
    #pragma unroll
    for (int j = 0; j < 5; ++j) {
      int idx = t + j * 256;           // 32*40 float4
      int r = idx / 40, c4 = idx % 40;
      float4 v = *reinterpret_cast<const float4*>(x + (long)r * 16000 + kc + c4 * 4);
      *reinterpret_cast<float4*>(&lx[r][c4 * 4]) = v;
    }
    __syncthreads();
    for (int kk = 0; kk < KB; kk += 4) {
      float4 xv0 = *reinterpret_cast<const float4*>(&lx[tg * 2 + 0][kk]);
      float4 xv1 = *reinterpret_cast<const float4*>(&lx[tg * 2 + 1][kk]);
      #pragma unroll
      for (int j = 0; j < 4; ++j) {
        float4 wv = *reinterpret_cast<const float4*>(&lw[rg * 4 + j][kk]);
        acc[j][0] += wv.x * xv0.x + wv.y * xv0.y + wv.z * xv0.z + wv.w * xv0.w;
        acc[j][1] += wv.x * xv1.x + wv.y * xv1.y + wv.z * xv1.z + wv.w * xv1.w;
      }
    }
  }
  #pragma unroll
  for (int j = 0; j < 4; ++j)
    #pragma unroll
    for (int u = 0; u < 2; ++u)
      atomicAdd(&ws[WS_GI + (tg * 2 + u) * G3 + m0 + rg * 4 + j], acc[j][u]);
}

__device__ __forceinline__ void load_wslice(const float* __restrict__ whh, int j0, int rg, int cg,
                                            float w[8][16]) {
  #pragma unroll
  for (int k = 0; k < 8; ++k) {
    const int lr = rg * 8 + k;
    const int grow = (lr >> 5) * HID + j0 + (lr & 31);
    const float* src = whh + grow * HID + cg * 16;
    #pragma unroll
    for (int q = 0; q < 4; ++q) {
      float4 v = *reinterpret_cast<const float4*>(src + q * 4);
      w[k][q * 4 + 0] = v.x; w[k][q * 4 + 1] = v.y;
      w[k][q * 4 + 2] = v.z; w[k][q * 4 + 3] = v.w;
    }
  }
}

__global__ __launch_bounds__(TPB) void k2_rnn(
    const float* __restrict__ enc_w_hh, const float* __restrict__ enc_b_hh,
    const float* __restrict__ dec_w_ih, const float* __restrict__ dec_w_hh,
    const float* __restrict__ dec_b_ih, const float* __restrict__ dec_b_hh,
    const float* __restrict__ lin_w, const float* __restrict__ lin_b,
    float* __restrict__ ws, float* __restrict__ out) {
  __shared__ float gsum[RPW];
  __shared__ float h_own[JPW];
  __shared__ float s_last[8];
  __shared__ float s_wih[RPW][6];
  __shared__ float s_bih[RPW];
  __shared__ float s_bhh[RPW];
  __shared__ float s_linw[6][JPW];
  __shared__ float s_linb[6];
  __shared__ float s_pm[NWG][6];

  const int wg = blockIdx.x;
  const int t  = threadIdx.x;
  const int rg = t >> 5;   // 12 row groups of 8 rows
  const int cg = t & 31;   // 32 col groups of 16 cols
  const int j0 = wg * JPW;

  unsigned* cnt = (unsigned*)ws;
  float* hex  = ws + WS_HEX;    // [2][HID]
  float* pmsg = ws + WS_PMSG;   // [2][NWG][8]
  const float* gi_enc = ws + WS_GI;

  float w[8][16];
  unsigned bstep = 0;
  int p = 0;

  // ---------------- stage A: encoder recurrence (32 steps) ----------------
  load_wslice(enc_w_hh, j0, rg, cg, w);
  if (t < RPW) {
    const int grow = (t >> 5) * HID + j0 + (t & 31);
    s_bhh[t] = enc_b_hh[grow];
  }
  if (t < JPW) h_own[t] = 0.0f;
  __syncthreads();

  for (int s = 0; s < 32; ++s) {
    float hr[16];
    {
      const float* hb = hex + p * HID + cg * 16;
      #pragma unroll
      for (int u = 0; u < 8; ++u) ld_agent2(hb + 2 * u, hr[2 * u], hr[2 * u + 1]);
    }
    float gi0 = 0.f, gi1 = 0.f, gi2 = 0.f;
    if (t < JPW) {
      const float* g = gi_enc + s * G3 + j0 + t;
      gi0 = g[0]; gi1 = g[HID]; gi2 = g[2 * HID];
    }
    float acc[8];
    #pragma unroll
    for (int k = 0; k < 8; ++k) {
      float a = 0.f;
      #pragma unroll
      for (int i = 0; i < 16; ++i) a = fmaf(w[k][i], hr[i], a);
      acc[k] = a;
    }
    #pragma unroll
    for (int m = 1; m <= 16; m <<= 1) {
      #pragma unroll
      for (int k = 0; k < 8; ++k) acc[k] += __shfl_xor(acc[k], m, 64);
    }
    if (cg == 0) {
      #pragma unroll
      for (int k = 0; k < 8; ++k) gsum[rg * 8 + k] = acc[k];
    }
    __syncthreads();
    if (t < JPW) {
      float r = sigmf(gi0 + gsum[t]      + s_bhh[t]);
      float z = sigmf(gi1 + gsum[32 + t] + s_bhh[32 + t]);
      float n = tanhf(gi2 + r * (gsum[64 + t] + s_bhh[64 + t]));
      float hn = (1.0f - z) * n + z * h_own[t];
      h_own[t] = hn;
      st_agent(&hex[(p ^ 1) * HID + j0 + t], hn);
    }
    p ^= 1;
    ++bstep;
    __syncthreads();
    if (t == 0) {
      __hip_atomic_fetch_add(cnt, 1u, __ATOMIC_ACQ_REL, __HIP_MEMORY_SCOPE_AGENT);
      const unsigned tgt = NWG * bstep;
      while (__hip_atomic_load(cnt, __ATOMIC_ACQUIRE, __HIP_MEMORY_SCOPE_AGENT) < tgt)
        __builtin_amdgcn_s_sleep(1);
    }
    __syncthreads();
  }

  // ---------------- stage B: decoder ----------------
  load_wslice(dec_w_hh, j0, rg, cg, w);
  if (t < RPW) {
    const int grow = (t >> 5) * HID + j0 + (t & 31);
    s_bih[t] = dec_b_ih[grow];
    s_bhh[t] = dec_b_hh[grow];
    #pragma unroll
    for (int m = 0; m < 6; ++m) s_wih[t][m] = dec_w_ih[grow * 6 + m];
  }
  if (t < 192) {
    const int m = t >> 5, jj = t & 31;
    s_linw[m][jj] = lin_w[m * HID + j0 + jj];
  }
  if (t < 6) s_linb[t] = lin_b[t];
  __syncthreads();

  int messages = 1;

  // k = 0: zero-input pre-step (gi = b_ih); k = 1..510: message loop
  for (int k = 0; k <= 510; ++k) {
    if (k >= 1) {
      const bool cond = (rintf(s_last[0]) != 2.0f) && (messages < 511);
      if (!cond) break;  // identical in every WG -> all break together
    }
    float hr[16];
    {
      const float* hb = hex + p * HID + cg * 16;
      #pragma unroll
      for (int u = 0; u < 8; ++u) ld_agent2(hb + 2 * u, hr[2 * u], hr[2 * u + 1]);
    }
    float acc[8];
    #pragma unroll
    for (int kk = 0; kk < 8; ++kk) {
      float a = 0.f;
      #pragma unroll
      for (int i = 0; i < 16; ++i) a = fmaf(w[kk][i], hr[i], a);
      acc[kk] = a;
    }
    #pragma unroll
    for (int m = 1; m <= 16; m <<= 1) {
      #pragma unroll
      for (int kk = 0; kk < 8; ++kk) acc[kk] += __shfl_xor(acc[kk], m, 64);
    }
    if (cg == 0) {
      #pragma unroll
      for (int kk = 0; kk < 8; ++kk) gsum[rg * 8 + kk] = acc[kk];
    }
    __syncthreads();
    if (t < JPW) {
      float gi0 = s_bih[t], gi1 = s_bih[32 + t], gi2 = s_bih[64 + t];
      if (k >= 1) {
        #pragma unroll
        for (int m = 0; m < 6; ++m) {
          gi0 = fmaf(s_wih[t][m],      s_last[m], gi0);
          gi1 = fmaf(s_wih[32 + t][m], s_last[m], gi1);
          gi2 = fmaf(s_wih[64 + t][m], s_last[m], gi2);
        }
      }
      float r = sigmf(gi0 + gsum[t]      + s_bhh[t]);
      float z = sigmf(gi1 + gsum[32 + t] + s_bhh[32 + t]);
      float n = tanhf(gi2 + r * (gsum[64 + t] + s_bhh[64 + t]));
      float hn = (1.0f - z) * n + z * h_own[t];
      h_own[t] = hn;
      st_agent(&hex[(p ^ 1) * HID + j0 + t], hn);
    }
    __syncthreads();
    if (t >= 32 && t < 38) {
      const int m = t - 32;
      float pm = 0.f;
      #pragma unroll
      for (int jj = 0; jj < JPW; ++jj) pm = fmaf(s_linw[m][jj], h_own[jj], pm);
      st_agent(&pmsg[(k & 1) * NWG * 8 + wg * 8 + m], pm);
    }
    p ^= 1;
    ++bstep;
    __syncthreads();
    if (t == 0) {
      __hip_atomic_fetch_add(cnt, 1u, __ATOMIC_ACQ_REL, __HIP_MEMORY_SCOPE_AGENT);
      const unsigned tgt = NWG * bstep;
      while (__hip_atomic_load(cnt, __ATOMIC_ACQUIRE, __HIP_MEMORY_SCOPE_AGENT) < tgt)
        __builtin_amdgcn_s_sleep(1);
    }
    __syncthreads();
    // finalize msg: gather partials (identical order in every WG -> bitwise-identical last)
    if (t >= 128 && t < 128 + NWG * 6) {
      const int wi = (t - 128) / 6, m = (t - 128) % 6;
      s_pm[wi][m] = ld_agent(&pmsg[(k & 1) * NWG * 8 + wi * 8 + m]);
    }
    __syncthreads();
    if (t < 6) {
      float sme = s_linb[t];
      #pragma unroll
      for (int wi = 0; wi < NWG; ++wi) sme += s_pm[wi][t];
      s_last[t] = sme;
      if (wg == 0) {
        const int row = (k == 0) ? 0 : (messages + 1);
        out[row * 6 + t] = sme;
      }
    }
    __syncthreads();
    if (k >= 1) ++messages;
  }

  if (wg == 0 && t == 0) out[3072] = (float)(messages + 1);
}

extern "C" void kernel_launch(void* const* d_in, const int* in_sizes, int n_in,
                              void* d_out, int out_size, void* d_ws, size_t ws_size,
                              hipStream_t stream) {
  const float* x        = (const float*)d_in[0];
  const float* enc_w_ih = (const float*)d_in[1];
  const float* enc_w_hh = (const float*)d_in[2];
  const float* enc_b_ih = (const float*)d_in[3];
  const float* enc_b_hh = (const float*)d_in[4];
  const float* dec_w_ih = (const float*)d_in[5];
  const float* dec_w_hh = (const float*)d_in[6];
  const float* dec_b_ih = (const float*)d_in[7];
  const float* dec_b_hh = (const float*)d_in[8];
  const float* lin_w    = (const float*)d_in[9];
  const float* lin_b    = (const float*)d_in[10];
  float* ws  = (float*)d_ws;
  float* out = (float*)d_out;

  hipLaunchKernelGGL(k0_init, dim3(64), dim3(256), 0, stream, ws, out, enc_b_ih);
  hipLaunchKernelGGL(k1_gemm, dim3(24, 10), dim3(256), 0, stream, x, enc_w_ih, ws);
  hipLaunchKernelGGL(k2_rnn, dim3(NWG), dim3(TPB), 0, stream,
                     enc_w_hh, enc_b_hh, dec_w_ih, dec_w_hh, dec_b_ih, dec_b_hh,
                     lin_w, lin_b, ws, out);
}